// Round 1
// baseline (4506.213 us; speedup 1.0000x reference)
//
#include <hip/hip_runtime.h>
#include <hip/hip_bf16.h>

#define D 128
#define G4 512   // 4*D
#define KK 256   // D + D (x part + h part)

typedef __attribute__((ext_vector_type(4))) float f32x4;
typedef __attribute__((ext_vector_type(8))) __bf16 bf16x8;

__device__ __forceinline__ float sigmoidf_(float x) {
    return 1.0f / (1.0f + __expf(-x));
}
__device__ __forceinline__ float tanhf_(float x) {
    float e = __expf(-2.0f * fabsf(x));   // in (0,1], no overflow
    float t = (1.0f - e) / (1.0f + e);
    return copysignf(t, x);
}

// ---------------- weight packing ----------------
// Wcomb[row][k] (bf16, [512][256]): k<128 -> W_ih[row][k], else W_hh[row][k-128]
// W1t[o][k] = W1[k][o], W2t likewise (bf16, [128][128])
// bcomb = b_ih + b_hh (fp32 [512])
__global__ void k_prep(const float* __restrict__ Wih, const float* __restrict__ Whh,
                       const float* __restrict__ bih, const float* __restrict__ bhh,
                       const float* __restrict__ W1, const float* __restrict__ W2,
                       __bf16* __restrict__ Wcomb, __bf16* __restrict__ W1t,
                       __bf16* __restrict__ W2t, float* __restrict__ bcomb) {
    int t = blockIdx.x * blockDim.x + threadIdx.x;
    if (t < G4 * KK) {
        int row = t / KK, k = t % KK;
        float v = (k < D) ? Wih[row * D + k] : Whh[row * D + (k - D)];
        Wcomb[t] = (__bf16)v;
    } else if (t < G4 * KK + D * D) {
        int u = t - G4 * KK; int o = u / D, k = u % D;
        W1t[u] = (__bf16)W1[k * D + o];
    } else if (t < G4 * KK + 2 * D * D) {
        int u = t - G4 * KK - D * D; int o = u / D, k = u % D;
        W2t[u] = (__bf16)W2[k * D + o];
    } else if (t < G4 * KK + 2 * D * D + G4) {
        int u = t - G4 * KK - 2 * D * D;
        bcomb[u] = bih[u] + bhh[u];
    }
}

// ---------------- persistent LSTM (+ fused xw1 = h @ W1) ----------------
// wave = 16 nodes; c-state in VGPRs; h kept as bf16 in wave-private LDS tile.
// gates = [x_t, h] @ Wcomb^T via mfma_f32_16x16x32_bf16.
// A-frag: lane l holds A[row = l&15][k = (l>>4)*8 + j] (8 consecutive k)
// B-frag: lane l holds B[k = (l>>4)*8 + j][col = l&15] = Wcomb[col][k] (row-contig)
// D-frag: lane l reg j -> D[row = (l>>4)*4 + j][col = l&15]
__global__ __launch_bounds__(256) void k_lstm(
        const float* __restrict__ xin, const __bf16* __restrict__ Wcomb,
        const float* __restrict__ bcomb, const __bf16* __restrict__ W1t,
        float* __restrict__ xw1, int n, int tsteps) {
    __shared__ __bf16 hbuf[4][16][D];   // 16 KB, wave-private slices
    const int tid = threadIdx.x;
    const int wid = tid >> 6, l = tid & 63, q = l >> 4, c16 = l & 15;
    const int wave = blockIdx.x * 4 + wid;
    const int R = wave * 16;
    const bool act = (R + 16 <= n);     // n % 16 == 0
    const int Rc = act ? R : 0;

    for (int i = l; i < 16 * D; i += 64) (&hbuf[wid][0][0])[i] = (__bf16)0.0f;
    __syncthreads();

    float bI[8], bF[8], bG[8], bO[8];
#pragma unroll
    for (int tb = 0; tb < 8; ++tb) {
        bI[tb] = bcomb[0 * D + tb * 16 + c16];
        bF[tb] = bcomb[1 * D + tb * 16 + c16];
        bG[tb] = bcomb[2 * D + tb * 16 + c16];
        bO[tb] = bcomb[3 * D + tb * 16 + c16];
    }
    float cs[8][4];
#pragma unroll
    for (int tb = 0; tb < 8; ++tb)
#pragma unroll
        for (int j = 0; j < 4; ++j) cs[tb][j] = 0.0f;

    for (int t = 0; t < tsteps; ++t) {
        bf16x8 ax[4], ah[4];
        const float* xrow = xin + ((size_t)t * n + (Rc + c16)) * D;
#pragma unroll
        for (int kb = 0; kb < 4; ++kb) {
            float4 v0 = *(const float4*)(xrow + kb * 32 + q * 8);
            float4 v1 = *(const float4*)(xrow + kb * 32 + q * 8 + 4);
            bf16x8 a;
            a[0] = (__bf16)v0.x; a[1] = (__bf16)v0.y; a[2] = (__bf16)v0.z; a[3] = (__bf16)v0.w;
            a[4] = (__bf16)v1.x; a[5] = (__bf16)v1.y; a[6] = (__bf16)v1.z; a[7] = (__bf16)v1.w;
            ax[kb] = a;
            ah[kb] = *(const bf16x8*)&hbuf[wid][c16][kb * 32 + q * 8];
        }
#pragma unroll
        for (int tb = 0; tb < 8; ++tb) {
            f32x4 acc0 = {0,0,0,0}, acc1 = {0,0,0,0}, acc2 = {0,0,0,0}, acc3 = {0,0,0,0};
#pragma unroll
            for (int kb = 0; kb < 8; ++kb) {
                bf16x8 a = (kb < 4) ? ax[kb] : ah[kb - 4];
                const __bf16* wb = Wcomb + (size_t)(tb * 16 + c16) * KK + (kb * 32 + q * 8);
                acc0 = __builtin_amdgcn_mfma_f32_16x16x32_bf16(a, *(const bf16x8*)(wb + 0 * 128 * KK), acc0, 0, 0, 0);
                acc1 = __builtin_amdgcn_mfma_f32_16x16x32_bf16(a, *(const bf16x8*)(wb + 1 * 128 * KK), acc1, 0, 0, 0);
                acc2 = __builtin_amdgcn_mfma_f32_16x16x32_bf16(a, *(const bf16x8*)(wb + 2 * 128 * KK), acc2, 0, 0, 0);
                acc3 = __builtin_amdgcn_mfma_f32_16x16x32_bf16(a, *(const bf16x8*)(wb + 3 * 128 * KK), acc3, 0, 0, 0);
            }
#pragma unroll
            for (int j = 0; j < 4; ++j) {
                float ii = sigmoidf_(acc0[j] + bI[tb]);
                float ff = sigmoidf_(acc1[j] + bF[tb]);
                float gg = tanhf_(acc2[j] + bG[tb]);
                float oo = sigmoidf_(acc3[j] + bO[tb]);
                float c = ff * cs[tb][j] + ii * gg;
                cs[tb][j] = c;
                float h = oo * tanhf_(c);
                hbuf[wid][q * 4 + j][tb * 16 + c16] = (__bf16)h;
            }
        }
        __syncthreads();
    }

    // epilogue: xw1 = h_final @ W1 (via W1t[o][k]); K = 128
    bf16x8 hf[4];
#pragma unroll
    for (int kb = 0; kb < 4; ++kb)
        hf[kb] = *(const bf16x8*)&hbuf[wid][c16][kb * 32 + q * 8];
#pragma unroll
    for (int nt = 0; nt < 8; ++nt) {
        f32x4 acc = {0,0,0,0};
#pragma unroll
        for (int kb = 0; kb < 4; ++kb) {
            const __bf16* wb = W1t + (size_t)(nt * 16 + c16) * D + (kb * 32 + q * 8);
            acc = __builtin_amdgcn_mfma_f32_16x16x32_bf16(hf[kb], *(const bf16x8*)wb, acc, 0, 0, 0);
        }
        if (act) {
#pragma unroll
            for (int j = 0; j < 4; ++j)
                xw1[(size_t)(R + q * 4 + j) * D + nt * 16 + c16] = acc[j];
        }
    }
}

// ---------------- xw2 = relu(out1) @ W2 ----------------
__global__ __launch_bounds__(256) void k_gemm_relu(
        const float* __restrict__ in, const __bf16* __restrict__ Wt,
        float* __restrict__ outm, int n) {
    const int tid = threadIdx.x, wid = tid >> 6, l = tid & 63, q = l >> 4, c16 = l & 15;
    const int R = (blockIdx.x * 4 + wid) * 16;
    if (R + 16 > n) return;   // no barriers in this kernel
    const float* row = in + (size_t)(R + c16) * D;
    bf16x8 af[4];
#pragma unroll
    for (int kb = 0; kb < 4; ++kb) {
        float4 v0 = *(const float4*)(row + kb * 32 + q * 8);
        float4 v1 = *(const float4*)(row + kb * 32 + q * 8 + 4);
        bf16x8 a;
        a[0] = (__bf16)fmaxf(v0.x, 0.f); a[1] = (__bf16)fmaxf(v0.y, 0.f);
        a[2] = (__bf16)fmaxf(v0.z, 0.f); a[3] = (__bf16)fmaxf(v0.w, 0.f);
        a[4] = (__bf16)fmaxf(v1.x, 0.f); a[5] = (__bf16)fmaxf(v1.y, 0.f);
        a[6] = (__bf16)fmaxf(v1.z, 0.f); a[7] = (__bf16)fmaxf(v1.w, 0.f);
        af[kb] = a;
    }
#pragma unroll
    for (int nt = 0; nt < 8; ++nt) {
        f32x4 acc = {0,0,0,0};
#pragma unroll
        for (int kb = 0; kb < 4; ++kb) {
            const __bf16* wb = Wt + (size_t)(nt * 16 + c16) * D + (kb * 32 + q * 8);
            acc = __builtin_amdgcn_mfma_f32_16x16x32_bf16(af[kb], *(const bf16x8*)wb, acc, 0, 0, 0);
        }
#pragma unroll
        for (int j = 0; j < 4; ++j)
            outm[(size_t)(R + q * 4 + j) * D + nt * 16 + c16] = acc[j];
    }
}

// ---------------- CSR build (histogram + scan + permute) ----------------
__global__ void k_zero(int* p, int n) {
    int i = blockIdx.x * blockDim.x + threadIdx.x;
    if (i < n) p[i] = 0;
}
__global__ void k_hist(const int* __restrict__ dst, int* __restrict__ counts, int e) {
    for (int i = blockIdx.x * blockDim.x + threadIdx.x; i < e; i += gridDim.x * blockDim.x)
        atomicAdd(&counts[dst[i]], 1);
}
__global__ __launch_bounds__(1024) void k_scan1(const int* __restrict__ counts,
        int* __restrict__ offsets, int* __restrict__ bsum, int n) {
    __shared__ int sd[1024];
    int tid = threadIdx.x, i = blockIdx.x * 1024 + tid;
    int v = (i < n) ? counts[i] : 0;
    sd[tid] = v; __syncthreads();
    for (int off = 1; off < 1024; off <<= 1) {
        int t = (tid >= off) ? sd[tid - off] : 0; __syncthreads();
        sd[tid] += t; __syncthreads();
    }
    if (i < n) offsets[i] = sd[tid] - v;      // exclusive, block-local
    if (tid == 1023) bsum[blockIdx.x] = sd[1023];
}
__global__ void k_scan2(const int* __restrict__ bsum, int* __restrict__ bpref, int nb) {
    if (threadIdx.x == 0) {
        int run = 0;
        for (int i = 0; i < nb; ++i) { bpref[i] = run; run += bsum[i]; }
    }
}
__global__ __launch_bounds__(1024) void k_scan3(int* __restrict__ offsets,
        int* __restrict__ cursor, const int* __restrict__ bpref, int n, int e) {
    int i = blockIdx.x * 1024 + threadIdx.x;
    if (i < n) {
        int v = offsets[i] + bpref[blockIdx.x];
        offsets[i] = v; cursor[i] = v;
    }
    if (i == 0) offsets[n] = e;
}
__global__ void k_permute(const int* __restrict__ src, const int* __restrict__ dst,
                          int* cursor, int* __restrict__ csr, int e) {
    for (int i = blockIdx.x * blockDim.x + threadIdx.x; i < e; i += gridDim.x * blockDim.x) {
        int p = atomicAdd(&cursor[dst[i]], 1);
        csr[p] = src[i];
    }
}

// ---------------- per-dst gather: out[d] = bias + sum_{src in CSR[d]} xw[src] ----------------
__global__ __launch_bounds__(256) void k_gather(const float* __restrict__ xw,
        const int* __restrict__ offsets, const int* __restrict__ csr,
        const float* __restrict__ bias, float* __restrict__ outp, int n) {
    int wid = threadIdx.x >> 6, l = threadIdx.x & 63;
    int d = blockIdx.x * 4 + wid;
    if (d >= n) return;
    int s = offsets[d], epos = offsets[d + 1];
    float ax = 0.f, ay = 0.f;
    int i = s;
    for (; i + 2 <= epos; i += 2) {
        int s0 = csr[i], s1 = csr[i + 1];
        float2 v0 = *(const float2*)(xw + (size_t)s0 * D + 2 * l);
        float2 v1 = *(const float2*)(xw + (size_t)s1 * D + 2 * l);
        ax += v0.x + v1.x; ay += v0.y + v1.y;
    }
    if (i < epos) {
        float2 v = *(const float2*)(xw + (size_t)csr[i] * D + 2 * l);
        ax += v.x; ay += v.y;
    }
    float2 bb = *(const float2*)(bias + 2 * l);
    float2 r; r.x = ax + bb.x; r.y = ay + bb.y;
    *(float2*)(outp + (size_t)d * D + 2 * l) = r;
}

extern "C" void kernel_launch(void* const* d_in, const int* in_sizes, int n_in,
                              void* d_out, int out_size, void* d_ws, size_t ws_size,
                              hipStream_t stream) {
    const float* xin = (const float*)d_in[0];
    const int*   edges = (const int*)d_in[1];
    const float* Wih = (const float*)d_in[2];
    const float* Whh = (const float*)d_in[3];
    const float* bih = (const float*)d_in[4];
    const float* bhh = (const float*)d_in[5];
    const float* W1  = (const float*)d_in[6];
    const float* b1  = (const float*)d_in[7];
    const float* W2  = (const float*)d_in[8];
    const float* b2  = (const float*)d_in[9];
    float* outp = (float*)d_out;

    const int E = in_sizes[1] / 2;
    const int n = out_size / D;                 // 50000
    const int tsteps = in_sizes[0] / (n * D);   // 16
    const int* srcE = edges;
    const int* dstE = edges + E;

    char* ws = (char*)d_ws;
    size_t off = 0;
    auto alloc = [&](size_t bytes) { void* p = ws + off; off += (bytes + 511) & ~(size_t)511; return p; };
    __bf16* Wcomb = (__bf16*)alloc((size_t)G4 * KK * 2);
    __bf16* W1t   = (__bf16*)alloc((size_t)D * D * 2);
    __bf16* W2t   = (__bf16*)alloc((size_t)D * D * 2);
    float*  bcomb = (float*)alloc((size_t)G4 * 4);
    int* counts  = (int*)alloc((size_t)(n + 1) * 4);
    int* offsets = (int*)alloc((size_t)(n + 1) * 4);
    int* cursor  = (int*)alloc((size_t)(n + 1) * 4);
    int* bsum    = (int*)alloc(64 * 4);
    int* bpref   = (int*)alloc(64 * 4);
    int* csr     = (int*)alloc((size_t)E * 4);
    float* xw1   = (float*)alloc((size_t)n * D * 4);
    float* out1  = (float*)alloc((size_t)n * D * 4);
    float* xw2   = xw1;   // reuse: xw1 dead after layer-1 gather
    (void)ws_size; (void)n_in;

    // weight packing
    {
        int total = G4 * KK + 2 * D * D + G4;
        k_prep<<<(total + 255) / 256, 256, 0, stream>>>(Wih, Whh, bih, bhh, W1, W2,
                                                        Wcomb, W1t, W2t, bcomb);
    }
    // CSR build (independent of LSTM; stream-ordered anyway)
    k_zero<<<(n + 255) / 256, 256, 0, stream>>>(counts, n);
    k_hist<<<2048, 256, 0, stream>>>(dstE, counts, E);
    int nb = (n + 1023) / 1024;
    k_scan1<<<nb, 1024, 0, stream>>>(counts, offsets, bsum, n);
    k_scan2<<<1, 64, 0, stream>>>(bsum, bpref, nb);
    k_scan3<<<nb, 1024, 0, stream>>>(offsets, cursor, bpref, n, E);
    k_permute<<<2048, 256, 0, stream>>>(srcE, dstE, cursor, csr, E);

    // LSTM (+ fused xw1 = h @ W1)
    {
        int waves = (n + 15) / 16;
        int blocks = (waves + 3) / 4;
        k_lstm<<<blocks, 256, 0, stream>>>(xin, Wcomb, bcomb, W1t, xw1, n, tsteps);
    }
    // layer 1: out1 = b1 + scatter(xw1)   (relu deferred into next GEMM's load)
    k_gather<<<(n + 3) / 4, 256, 0, stream>>>(xw1, offsets, csr, b1, out1, n);
    // xw2 = relu(out1) @ W2
    {
        int waves = (n + 15) / 16;
        int blocks = (waves + 3) / 4;
        k_gemm_relu<<<blocks, 256, 0, stream>>>(out1, W2t, xw2, n);
    }
    // layer 2: out = b2 + scatter(xw2)
    k_gather<<<(n + 3) / 4, 256, 0, stream>>>(xw2, offsets, csr, b2, outp, n);
}

// Round 2
// 1105.116 us; speedup vs baseline: 4.0776x; 4.0776x over previous
//
#include <hip/hip_runtime.h>
#include <hip/hip_bf16.h>

#define D 128
#define G4 512   // 4*D
#define KK 256   // D + D (x part + h part)

typedef __attribute__((ext_vector_type(4))) float f32x4;
typedef __attribute__((ext_vector_type(8))) __bf16 bf16x8;
typedef __attribute__((ext_vector_type(8))) unsigned short u16x8;

__device__ __forceinline__ float sigm2(float x) {
    // 1/(1+2^(-x*log2e))
    return __builtin_amdgcn_rcpf(1.0f + __builtin_amdgcn_exp2f(-1.4426950408889634f * x));
}
__device__ __forceinline__ float tanh2(float x) {
    // 1 - 2/(1+2^(2x*log2e)); exp2 overflow -> inf -> rcp=0 -> 1 (correct saturation)
    return 1.0f - 2.0f * __builtin_amdgcn_rcpf(1.0f + __builtin_amdgcn_exp2f(2.8853900817779268f * x));
}
__device__ __forceinline__ float bf_lo(unsigned int u) { return __uint_as_float(u << 16); }
__device__ __forceinline__ float bf_hi(unsigned int u) { return __uint_as_float(u & 0xffff0000u); }

// ---------------- weight packing ----------------
// Wcomb[row][k] (bf16, [512][256]): k<128 -> W_ih[row][k], else W_hh[row][k-128]
// W1t[o][k] = W1[k][o], W2t likewise (bf16, [128][128]); bcomb = b_ih + b_hh (fp32 [512])
__global__ void k_prep(const float* __restrict__ Wih, const float* __restrict__ Whh,
                       const float* __restrict__ bih, const float* __restrict__ bhh,
                       const float* __restrict__ W1, const float* __restrict__ W2,
                       __bf16* __restrict__ Wcomb, __bf16* __restrict__ W1t,
                       __bf16* __restrict__ W2t, float* __restrict__ bcomb) {
    int t = blockIdx.x * blockDim.x + threadIdx.x;
    if (t < G4 * KK) {
        int row = t / KK, k = t % KK;
        float v = (k < D) ? Wih[row * D + k] : Whh[row * D + (k - D)];
        Wcomb[t] = (__bf16)v;
    } else if (t < G4 * KK + D * D) {
        int u = t - G4 * KK; int o = u / D, k = u % D;
        W1t[u] = (__bf16)W1[k * D + o];
    } else if (t < G4 * KK + 2 * D * D) {
        int u = t - G4 * KK - D * D; int o = u / D, k = u % D;
        W2t[u] = (__bf16)W2[k * D + o];
    } else if (t < G4 * KK + 2 * D * D + G4) {
        int u = t - G4 * KK - 2 * D * D;
        bcomb[u] = bih[u] + bhh[u];
    }
}

// ---------------- persistent LSTM, weights in VGPRs ----------------
// Block = 8 waves (512 thr). Wave w holds B-frags for gate-outputs [w*64, w*64+64)
// over all K=256 in 128 VGPRs. Chunk = 16 nodes; x/h staged in XOR-swizzled LDS
// (shared across waves); gate pre-activations exchanged via padded fp32 LDS;
// cell update partitioned by dim: wave w owns dims [w*16, w*16+16), c in VGPRs.
// Epilogue: xw1 = h_final @ W1 (bf16 out).
__global__ __launch_bounds__(512, 2) void k_lstm2(
        const float* __restrict__ xin, const __bf16* __restrict__ Wcomb,
        const float* __restrict__ bcomb, const __bf16* __restrict__ W1t,
        __bf16* __restrict__ xw1, int n, int tsteps, int nchunks) {
    __shared__ float  gbuf[16][516];   // [node][gate*128+dim], +4 pad vs 512
    __shared__ __bf16 xbuf[16][D];     // swizzled: elem ^= (row&7)<<3
    __shared__ __bf16 hbuf[16][D];     // swizzled

    const int tid = threadIdx.x;
    const int wid = tid >> 6, l = tid & 63, q = l >> 4, c16 = l & 15;
    const int dim = wid * 16 + c16;

    // resident weight fragments: Wf[ct][kb] covers cols w*64+ct*16(+c16), k = kb*32+q*8..+8
    bf16x8 Wf[4][8];
#pragma unroll
    for (int ct = 0; ct < 4; ++ct)
#pragma unroll
        for (int kb = 0; kb < 8; ++kb)
            Wf[ct][kb] = *(const bf16x8*)(Wcomb + (size_t)(wid * 64 + ct * 16 + c16) * KK + kb * 32 + q * 8);

    const float bI = bcomb[0 * D + dim], bF = bcomb[1 * D + dim],
                bG = bcomb[2 * D + dim], bO = bcomb[3 * D + dim];

    const int srow = tid >> 4, sc8 = (tid & 15) * 8;   // staging coords (tid<256)

    for (int chunk = blockIdx.x; chunk < nchunks; chunk += gridDim.x) {
        const int R = chunk * 16;
        float cst[4] = {0.f, 0.f, 0.f, 0.f};

        if (tid < 256) {
            ((float4*)hbuf)[tid] = make_float4(0.f, 0.f, 0.f, 0.f);   // h0 = 0
            const float* xp = xin + ((size_t)(R + srow)) * D + sc8;   // t = 0
            float4 v0 = *(const float4*)xp, v1 = *(const float4*)(xp + 4);
            bf16x8 b;
            b[0] = (__bf16)v0.x; b[1] = (__bf16)v0.y; b[2] = (__bf16)v0.z; b[3] = (__bf16)v0.w;
            b[4] = (__bf16)v1.x; b[5] = (__bf16)v1.y; b[6] = (__bf16)v1.z; b[7] = (__bf16)v1.w;
            *(bf16x8*)&xbuf[srow][sc8 ^ ((srow & 7) << 3)] = b;
        }
        __syncthreads();

        for (int t = 0; t < tsteps; ++t) {
            // prefetch x(t+1) into regs (covered by MFMA phase + barrier)
            float4 p0, p1;
            const bool pf = (t + 1 < tsteps) && (tid < 256);
            if (pf) {
                const float* xp = xin + ((size_t)(t + 1) * n + R + srow) * D + sc8;
                p0 = *(const float4*)xp; p1 = *(const float4*)(xp + 4);
            }

            bf16x8 a[8];
#pragma unroll
            for (int kb = 0; kb < 4; ++kb)
                a[kb] = *(const bf16x8*)&xbuf[c16][(kb * 32 + q * 8) ^ ((c16 & 7) << 3)];
#pragma unroll
            for (int kb = 0; kb < 4; ++kb)
                a[4 + kb] = *(const bf16x8*)&hbuf[c16][(kb * 32 + q * 8) ^ ((c16 & 7) << 3)];

            f32x4 acc[4] = {{0,0,0,0},{0,0,0,0},{0,0,0,0},{0,0,0,0}};
#pragma unroll
            for (int kb = 0; kb < 8; ++kb)
#pragma unroll
                for (int ct = 0; ct < 4; ++ct)
                    acc[ct] = __builtin_amdgcn_mfma_f32_16x16x32_bf16(a[kb], Wf[ct][kb], acc[ct], 0, 0, 0);

#pragma unroll
            for (int ct = 0; ct < 4; ++ct)
#pragma unroll
                for (int j = 0; j < 4; ++j)
                    gbuf[q * 4 + j][wid * 64 + ct * 16 + c16] = acc[ct][j];
            __syncthreads();

            // cell update: lane owns (node = q*4+j, dim)
#pragma unroll
            for (int j = 0; j < 4; ++j) {
                const int node = q * 4 + j;
                float gi = gbuf[node][0 * D + dim];
                float gf = gbuf[node][1 * D + dim];
                float gg = gbuf[node][2 * D + dim];
                float go = gbuf[node][3 * D + dim];
                float iv = sigm2(gi + bI);
                float fv = sigm2(gf + bF);
                float gv = tanh2(gg + bG);
                float ov = sigm2(go + bO);
                float c = fv * cst[j] + iv * gv;
                cst[j] = c;
                float h = ov * tanh2(c);
                hbuf[node][dim ^ ((node & 7) << 3)] = (__bf16)h;
            }
            if (pf) {
                bf16x8 b;
                b[0] = (__bf16)p0.x; b[1] = (__bf16)p0.y; b[2] = (__bf16)p0.z; b[3] = (__bf16)p0.w;
                b[4] = (__bf16)p1.x; b[5] = (__bf16)p1.y; b[6] = (__bf16)p1.z; b[7] = (__bf16)p1.w;
                *(bf16x8*)&xbuf[srow][sc8 ^ ((srow & 7) << 3)] = b;
            }
            __syncthreads();
        }

        // epilogue: xw1[R..R+16) cols [wid*16, wid*16+16) = h_final @ W1
        f32x4 acc1 = {0, 0, 0, 0};
#pragma unroll
        for (int kb = 0; kb < 4; ++kb) {
            bf16x8 a = *(const bf16x8*)&hbuf[c16][(kb * 32 + q * 8) ^ ((c16 & 7) << 3)];
            bf16x8 wf = *(const bf16x8*)(W1t + (size_t)(wid * 16 + c16) * D + kb * 32 + q * 8);
            acc1 = __builtin_amdgcn_mfma_f32_16x16x32_bf16(a, wf, acc1, 0, 0, 0);
        }
#pragma unroll
        for (int j = 0; j < 4; ++j)
            xw1[(size_t)(R + q * 4 + j) * D + wid * 16 + c16] = (__bf16)acc1[j];
        __syncthreads();   // protect hbuf/xbuf before next chunk's restage
    }
}

// ---------------- xw2 = relu(out1) @ W2  (bf16 in / bf16 out) ----------------
__global__ __launch_bounds__(256) void k_gemm2(
        const __bf16* __restrict__ in, const __bf16* __restrict__ Wt,
        __bf16* __restrict__ outm, int n) {
    const int tid = threadIdx.x, wid = tid >> 6, l = tid & 63, q = l >> 4, c16 = l & 15;
    const int R = (blockIdx.x * 4 + wid) * 16;
    if (R + 16 > n) return;
    bf16x8 af[4];
#pragma unroll
    for (int kb = 0; kb < 4; ++kb) {
        u16x8 v = *(const u16x8*)((const unsigned short*)in + (size_t)(R + c16) * D + kb * 32 + q * 8);
#pragma unroll
        for (int j = 0; j < 8; ++j)
            if (v[j] & 0x8000u) v[j] = 0;    // relu on bf16 bits
        af[kb] = *(bf16x8*)&v;
    }
#pragma unroll
    for (int nt = 0; nt < 8; ++nt) {
        f32x4 acc = {0, 0, 0, 0};
#pragma unroll
        for (int kb = 0; kb < 4; ++kb) {
            const __bf16* wb = Wt + (size_t)(nt * 16 + c16) * D + (kb * 32 + q * 8);
            acc = __builtin_amdgcn_mfma_f32_16x16x32_bf16(af[kb], *(const bf16x8*)wb, acc, 0, 0, 0);
        }
#pragma unroll
        for (int j = 0; j < 4; ++j)
            outm[(size_t)(R + q * 4 + j) * D + nt * 16 + c16] = (__bf16)acc[j];
    }
}

// ---------------- CSR build (histogram + scan + permute) ----------------
__global__ void k_zero(int* p, int n) {
    int i = blockIdx.x * blockDim.x + threadIdx.x;
    if (i < n) p[i] = 0;
}
__global__ void k_hist(const int* __restrict__ dst, int* __restrict__ counts, int e) {
    for (int i = blockIdx.x * blockDim.x + threadIdx.x; i < e; i += gridDim.x * blockDim.x)
        atomicAdd(&counts[dst[i]], 1);
}
__global__ __launch_bounds__(1024) void k_scan1(const int* __restrict__ counts,
        int* __restrict__ offsets, int* __restrict__ bsum, int n) {
    __shared__ int sd[1024];
    int tid = threadIdx.x, i = blockIdx.x * 1024 + tid;
    int v = (i < n) ? counts[i] : 0;
    sd[tid] = v; __syncthreads();
    for (int off = 1; off < 1024; off <<= 1) {
        int t = (tid >= off) ? sd[tid - off] : 0; __syncthreads();
        sd[tid] += t; __syncthreads();
    }
    if (i < n) offsets[i] = sd[tid] - v;
    if (tid == 1023) bsum[blockIdx.x] = sd[1023];
}
__global__ void k_scan2(const int* __restrict__ bsum, int* __restrict__ bpref, int nb) {
    if (threadIdx.x == 0) {
        int run = 0;
        for (int i = 0; i < nb; ++i) { bpref[i] = run; run += bsum[i]; }
    }
}
__global__ __launch_bounds__(1024) void k_scan3(int* __restrict__ offsets,
        int* __restrict__ cursor, const int* __restrict__ bpref, int n, int e) {
    int i = blockIdx.x * 1024 + threadIdx.x;
    if (i < n) {
        int v = offsets[i] + bpref[blockIdx.x];
        offsets[i] = v; cursor[i] = v;
    }
    if (i == 0) offsets[n] = e;
}
__global__ void k_permute(const int* __restrict__ src, const int* __restrict__ dst,
                          int* cursor, int* __restrict__ csr, int e) {
    for (int i = blockIdx.x * blockDim.x + threadIdx.x; i < e; i += gridDim.x * blockDim.x) {
        int p = atomicAdd(&cursor[dst[i]], 1);
        csr[p] = src[i];
    }
}

// ---------------- per-dst gather over bf16 rows ----------------
// wave per dst; lane covers dims {2l, 2l+1} (4B/lane -> 256B/row, fully coalesced)
template <bool OUT_F32>
__global__ __launch_bounds__(256) void k_gather2(const __bf16* __restrict__ xw,
        const int* __restrict__ offsets, const int* __restrict__ csr,
        const float* __restrict__ bias, void* __restrict__ outp, int n) {
    int wid = threadIdx.x >> 6, l = threadIdx.x & 63;
    int d = blockIdx.x * 4 + wid;
    if (d >= n) return;
    int s = offsets[d], e = offsets[d + 1];
    const unsigned int* xu = (const unsigned int*)xw;
    float a0 = 0.f, a1 = 0.f;
    int i = s;
    for (; i + 4 <= e; i += 4) {
        unsigned int u0 = xu[(size_t)csr[i]     * 64 + l];
        unsigned int u1 = xu[(size_t)csr[i + 1] * 64 + l];
        unsigned int u2 = xu[(size_t)csr[i + 2] * 64 + l];
        unsigned int u3 = xu[(size_t)csr[i + 3] * 64 + l];
        a0 += (bf_lo(u0) + bf_lo(u1)) + (bf_lo(u2) + bf_lo(u3));
        a1 += (bf_hi(u0) + bf_hi(u1)) + (bf_hi(u2) + bf_hi(u3));
    }
    for (; i < e; ++i) {
        unsigned int u = xu[(size_t)csr[i] * 64 + l];
        a0 += bf_lo(u); a1 += bf_hi(u);
    }
    float2 bb = *(const float2*)(bias + 2 * l);
    float r0 = a0 + bb.x, r1 = a1 + bb.y;
    if (OUT_F32) {
        float2* o = (float2*)outp;
        o[(size_t)d * 64 + l] = make_float2(r0, r1);
    } else {
        __bf16* o = (__bf16*)outp;
        o[(size_t)d * D + 2 * l]     = (__bf16)r0;
        o[(size_t)d * D + 2 * l + 1] = (__bf16)r1;
    }
}

extern "C" void kernel_launch(void* const* d_in, const int* in_sizes, int n_in,
                              void* d_out, int out_size, void* d_ws, size_t ws_size,
                              hipStream_t stream) {
    const float* xin = (const float*)d_in[0];
    const int*   edges = (const int*)d_in[1];
    const float* Wih = (const float*)d_in[2];
    const float* Whh = (const float*)d_in[3];
    const float* bih = (const float*)d_in[4];
    const float* bhh = (const float*)d_in[5];
    const float* W1  = (const float*)d_in[6];
    const float* b1  = (const float*)d_in[7];
    const float* W2  = (const float*)d_in[8];
    const float* b2  = (const float*)d_in[9];
    float* outp = (float*)d_out;

    const int E = in_sizes[1] / 2;
    const int n = out_size / D;                 // 50000
    const int tsteps = in_sizes[0] / (n * D);   // 16
    const int* srcE = edges;
    const int* dstE = edges + E;

    char* ws = (char*)d_ws;
    size_t off = 0;
    auto alloc = [&](size_t bytes) { void* p = ws + off; off += (bytes + 511) & ~(size_t)511; return p; };
    __bf16* Wcomb = (__bf16*)alloc((size_t)G4 * KK * 2);
    __bf16* W1t   = (__bf16*)alloc((size_t)D * D * 2);
    __bf16* W2t   = (__bf16*)alloc((size_t)D * D * 2);
    float*  bcomb = (float*)alloc((size_t)G4 * 4);
    int* counts  = (int*)alloc((size_t)(n + 1) * 4);
    int* offsets = (int*)alloc((size_t)(n + 1) * 4);
    int* cursor  = (int*)alloc((size_t)(n + 1) * 4);
    int* bsum    = (int*)alloc(64 * 4);
    int* bpref   = (int*)alloc(64 * 4);
    int* csr     = (int*)alloc((size_t)E * 4);
    __bf16* xw1  = (__bf16*)alloc((size_t)n * D * 2);
    __bf16* out1 = (__bf16*)alloc((size_t)n * D * 2);
    __bf16* xw2  = xw1;   // reuse: xw1 dead after layer-1 gather
    (void)ws_size; (void)n_in;

    // weight packing
    {
        int total = G4 * KK + 2 * D * D + G4;
        k_prep<<<(total + 255) / 256, 256, 0, stream>>>(Wih, Whh, bih, bhh, W1, W2,
                                                        Wcomb, W1t, W2t, bcomb);
    }
    // CSR build
    k_zero<<<(n + 255) / 256, 256, 0, stream>>>(counts, n);
    k_hist<<<2048, 256, 0, stream>>>(dstE, counts, E);
    int nb = (n + 1023) / 1024;
    k_scan1<<<nb, 1024, 0, stream>>>(counts, offsets, bsum, n);
    k_scan2<<<1, 64, 0, stream>>>(bsum, bpref, nb);
    k_scan3<<<nb, 1024, 0, stream>>>(offsets, cursor, bpref, n, E);
    k_permute<<<2048, 256, 0, stream>>>(srcE, dstE, cursor, csr, E);

    // LSTM with register-resident weights (+ fused xw1 = h @ W1, bf16 out)
    k_lstm2<<<256, 512, 0, stream>>>(xin, Wcomb, bcomb, W1t, xw1, n, tsteps, n / 16);

    // layer 1: out1 = b1 + scatter(xw1)   (relu deferred into k_gemm2's load)
    k_gather2<false><<<(n + 3) / 4, 256, 0, stream>>>(xw1, offsets, csr, b1, out1, n);
    // xw2 = relu(out1) @ W2
    k_gemm2<<<((n / 16) + 3) / 4, 256, 0, stream>>>(out1, W2t, xw2, n);
    // layer 2: out = b2 + scatter(xw2), fp32
    k_gather2<true><<<(n + 3) / 4, 256, 0, stream>>>(xw2, offsets, csr, b2, outp, n);
}

// Round 4
// 1043.175 us; speedup vs baseline: 4.3197x; 1.0594x over previous
//
#include <hip/hip_runtime.h>
#include <hip/hip_bf16.h>

#define D 128
#define G4 512   // 4*D
#define KK 256   // D + D (x part + h part)

typedef __attribute__((ext_vector_type(4))) float f32x4;
typedef __attribute__((ext_vector_type(8))) __bf16 bf16x8;
typedef __attribute__((ext_vector_type(8))) unsigned short u16x8;
typedef __attribute__((ext_vector_type(4))) unsigned int u32x4;

__device__ __forceinline__ float sigm2(float x) {
    return __builtin_amdgcn_rcpf(1.0f + __builtin_amdgcn_exp2f(-1.4426950408889634f * x));
}
__device__ __forceinline__ float tanh2(float x) {
    return 1.0f - 2.0f * __builtin_amdgcn_rcpf(1.0f + __builtin_amdgcn_exp2f(2.8853900817779268f * x));
}
__device__ __forceinline__ float bf_lo(unsigned int u) { return __uint_as_float(u << 16); }
__device__ __forceinline__ float bf_hi(unsigned int u) { return __uint_as_float(u & 0xffff0000u); }

// ---------------- weight packing ----------------
__global__ void k_prep(const float* __restrict__ Wih, const float* __restrict__ Whh,
                       const float* __restrict__ bih, const float* __restrict__ bhh,
                       const float* __restrict__ W1, const float* __restrict__ W2,
                       __bf16* __restrict__ Wcomb, __bf16* __restrict__ W1t,
                       __bf16* __restrict__ W2t, float* __restrict__ bcomb) {
    int t = blockIdx.x * blockDim.x + threadIdx.x;
    if (t < G4 * KK) {
        int row = t / KK, k = t % KK;
        float v = (k < D) ? Wih[row * D + k] : Whh[row * D + (k - D)];
        Wcomb[t] = (__bf16)v;
    } else if (t < G4 * KK + D * D) {
        int u = t - G4 * KK; int o = u / D, k = u % D;
        W1t[u] = (__bf16)W1[k * D + o];
    } else if (t < G4 * KK + 2 * D * D) {
        int u = t - G4 * KK - D * D; int o = u / D, k = u % D;
        W2t[u] = (__bf16)W2[k * D + o];
    } else if (t < G4 * KK + 2 * D * D + G4) {
        int u = t - G4 * KK - 2 * D * D;
        bcomb[u] = bih[u] + bhh[u];
    }
}

// ---------------- persistent LSTM: pinned weights, 2 chunks/block, no gbuf ----------------
// Block = 8 waves. Wave w owns gate-cols {g*128 + w*16 + c16 : g=0..3} over K=256
// (128 pinned VGPRs). acc[g][j] directly gives i,f,g,o for (node q*4+j, dim w*16+c16)
// -> no LDS gate exchange. Two chunks (A,B) interleaved so chunk-B MFMAs overlap
// chunk-A activation VALU. x/h double-buffered in XOR-swizzled LDS; 1 barrier/t.
__global__ __launch_bounds__(512, 1) void k_lstm3(
        const float* __restrict__ xin, const __bf16* __restrict__ Wcomb,
        const float* __restrict__ bcomb, const __bf16* __restrict__ W1t,
        __bf16* __restrict__ xw1, int n, int tsteps, int npairs, int nchunks) {
    __shared__ __bf16 xb[2][2][16][D];   // [chunk][dbuf][node][elem^((node&7)<<3)]
    __shared__ __bf16 hb[2][2][16][D];

    const int tid = threadIdx.x;
    const int wid = tid >> 6, l = tid & 63, q = l >> 4, c16 = l & 15;
    const int dim = wid * 16 + c16;

    // pinned resident weights: Wf[g][kb] = B-frag for col g*128+dim, k in [kb*32, kb*32+32)
    bf16x8 Wf[4][8];
#pragma unroll
    for (int g = 0; g < 4; ++g)
#pragma unroll
        for (int kb = 0; kb < 8; ++kb)
            Wf[g][kb] = *(const bf16x8*)(Wcomb + (size_t)(g * D + dim) * KK + kb * 32 + q * 8);
#pragma unroll
    for (int g = 0; g < 4; ++g)
#pragma unroll
        for (int kb = 0; kb < 8; ++kb) {
            f32x4 tmp = __builtin_bit_cast(f32x4, Wf[g][kb]);
            asm volatile("" : "+v"(tmp));          // opaque def: forces VGPR residency
            Wf[g][kb] = __builtin_bit_cast(bf16x8, tmp);
        }

    const float bI = bcomb[0 * D + dim], bF = bcomb[1 * D + dim],
                bG = bcomb[2 * D + dim], bO = bcomb[3 * D + dim];

    const int sid = tid >> 8;                  // which chunk this thread stages
    const int su = tid & 255;
    const int srow = su >> 4, sc8 = (su & 15) * 8;
    const int fin = tsteps & 1;                // dbuf holding h_final / reused for epi

    for (int p = blockIdx.x; p < npairs; p += gridDim.x) {
        const int cA = 2 * p, cB = 2 * p + 1;
        const bool hasB = (cB < nchunks);
        const int myc = sid ? (hasB ? cB : cA) : cA;

        // zero h0; stage x(0)
        ((float4*)&hb[sid][0][0][0])[su] = make_float4(0.f, 0.f, 0.f, 0.f);
        {
            const float* xp = xin + ((size_t)(myc * 16 + srow)) * D + sc8;
            float4 v0 = *(const float4*)xp, v1 = *(const float4*)(xp + 4);
            bf16x8 b;
            b[0] = (__bf16)v0.x; b[1] = (__bf16)v0.y; b[2] = (__bf16)v0.z; b[3] = (__bf16)v0.w;
            b[4] = (__bf16)v1.x; b[5] = (__bf16)v1.y; b[6] = (__bf16)v1.z; b[7] = (__bf16)v1.w;
            *(bf16x8*)&xb[sid][0][srow][sc8 ^ ((srow & 7) << 3)] = b;
        }
        __syncthreads();

        float csA[4] = {0.f, 0.f, 0.f, 0.f}, csB[4] = {0.f, 0.f, 0.f, 0.f};

        for (int t = 0; t < tsteps; ++t) {
            const int cur = t & 1, nxt = cur ^ 1;

            bf16x8 aA[8], aB[8];
#pragma unroll
            for (int kb = 0; kb < 4; ++kb) {
                const int e = (kb * 32 + q * 8) ^ ((c16 & 7) << 3);
                aA[kb]     = *(const bf16x8*)&xb[0][cur][c16][e];
                aA[4 + kb] = *(const bf16x8*)&hb[0][cur][c16][e];
                aB[kb]     = *(const bf16x8*)&xb[1][cur][c16][e];
                aB[4 + kb] = *(const bf16x8*)&hb[1][cur][c16][e];
            }

            // prefetch x(t+1) for my chunk (hidden under MFMA phase)
            float4 p0, p1;
            const bool pf = (t + 1 < tsteps);
            if (pf) {
                const float* xp = xin + ((size_t)(t + 1) * n + myc * 16 + srow) * D + sc8;
                p0 = *(const float4*)xp; p1 = *(const float4*)(xp + 4);
            }

            f32x4 accA[4] = {{0,0,0,0},{0,0,0,0},{0,0,0,0},{0,0,0,0}};
            f32x4 accB[4] = {{0,0,0,0},{0,0,0,0},{0,0,0,0},{0,0,0,0}};
#pragma unroll
            for (int kb = 0; kb < 8; ++kb)
#pragma unroll
                for (int g = 0; g < 4; ++g) {
                    accA[g] = __builtin_amdgcn_mfma_f32_16x16x32_bf16(aA[kb], Wf[g][kb], accA[g], 0, 0, 0);
                    accB[g] = __builtin_amdgcn_mfma_f32_16x16x32_bf16(aB[kb], Wf[g][kb], accB[g], 0, 0, 0);
                }

            if (pf) {
                bf16x8 b;
                b[0] = (__bf16)p0.x; b[1] = (__bf16)p0.y; b[2] = (__bf16)p0.z; b[3] = (__bf16)p0.w;
                b[4] = (__bf16)p1.x; b[5] = (__bf16)p1.y; b[6] = (__bf16)p1.z; b[7] = (__bf16)p1.w;
                *(bf16x8*)&xb[sid][nxt][srow][sc8 ^ ((srow & 7) << 3)] = b;
            }

            // cell updates (regs only; i,f,g,o = acc[0..3][j])
#pragma unroll
            for (int j = 0; j < 4; ++j) {
                const int node = j + q * 4;
                {
                    float iv = sigm2(accA[0][j] + bI);
                    float fv = sigm2(accA[1][j] + bF);
                    float gv = tanh2(accA[2][j] + bG);
                    float ov = sigm2(accA[3][j] + bO);
                    float c = fv * csA[j] + iv * gv;
                    csA[j] = c;
                    hb[0][nxt][node][dim ^ ((node & 7) << 3)] = (__bf16)(ov * tanh2(c));
                }
                {
                    float iv = sigm2(accB[0][j] + bI);
                    float fv = sigm2(accB[1][j] + bF);
                    float gv = tanh2(accB[2][j] + bG);
                    float ov = sigm2(accB[3][j] + bO);
                    float c = fv * csB[j] + iv * gv;
                    csB[j] = c;
                    hb[1][nxt][node][dim ^ ((node & 7) << 3)] = (__bf16)(ov * tanh2(c));
                }
            }
            __syncthreads();
        }

        // epilogue: xw1 = h_final @ W1 for both chunks; stage via LDS for coalesced store
        bf16x8 hA[4], hB[4];
#pragma unroll
        for (int kb = 0; kb < 4; ++kb) {
            const int e = (kb * 32 + q * 8) ^ ((c16 & 7) << 3);
            hA[kb] = *(const bf16x8*)&hb[0][fin][c16][e];
            hB[kb] = *(const bf16x8*)&hb[1][fin][c16][e];
        }
        f32x4 eA = {0,0,0,0}, eB = {0,0,0,0};
#pragma unroll
        for (int kb = 0; kb < 4; ++kb) {
            bf16x8 wf = *(const bf16x8*)(W1t + (size_t)dim * D + kb * 32 + q * 8);
            eA = __builtin_amdgcn_mfma_f32_16x16x32_bf16(hA[kb], wf, eA, 0, 0, 0);
            eB = __builtin_amdgcn_mfma_f32_16x16x32_bf16(hB[kb], wf, eB, 0, 0, 0);
        }
#pragma unroll
        for (int j = 0; j < 4; ++j) {
            const int node = j + q * 4;
            xb[0][1][node][dim] = (__bf16)eA[j];   // xb[*][1] dead after t-loop (tsteps even)
            xb[1][1][node][dim] = (__bf16)eB[j];
        }
        __syncthreads();
        if (!(sid == 1 && !hasB))
            *(bf16x8*)(xw1 + (size_t)(myc * 16 + srow) * D + sc8) = *(const bf16x8*)&xb[sid][1][srow][sc8];
        __syncthreads();   // stores/reads of xb[*][1] done before next pair's writes
    }
}

// ---------------- xw2 = out1 @ W2  (out1 already relu'd bf16) ----------------
__global__ __launch_bounds__(256) void k_gemm2(
        const __bf16* __restrict__ in, const __bf16* __restrict__ Wt,
        __bf16* __restrict__ outm, int n) {
    const int tid = threadIdx.x, wid = tid >> 6, l = tid & 63, q = l >> 4, c16 = l & 15;
    const int R = (blockIdx.x * 4 + wid) * 16;
    if (R + 16 > n) return;
    bf16x8 af[4];
#pragma unroll
    for (int kb = 0; kb < 4; ++kb)
        af[kb] = *(const bf16x8*)(in + (size_t)(R + c16) * D + kb * 32 + q * 8);
#pragma unroll
    for (int nt = 0; nt < 8; ++nt) {
        f32x4 acc = {0, 0, 0, 0};
#pragma unroll
        for (int kb = 0; kb < 4; ++kb) {
            const __bf16* wb = Wt + (size_t)(nt * 16 + c16) * D + (kb * 32 + q * 8);
            acc = __builtin_amdgcn_mfma_f32_16x16x32_bf16(af[kb], *(const bf16x8*)wb, acc, 0, 0, 0);
        }
#pragma unroll
        for (int j = 0; j < 4; ++j)
            outm[(size_t)(R + q * 4 + j) * D + nt * 16 + c16] = (__bf16)acc[j];
    }
}

// ---------------- CSR build ----------------
__global__ void k_hist(const int* __restrict__ dst, int* __restrict__ counts, int e) {
    for (int i = blockIdx.x * blockDim.x + threadIdx.x; i < e; i += gridDim.x * blockDim.x)
        atomicAdd(&counts[dst[i]], 1);
}
__global__ __launch_bounds__(1024) void k_scan1(const int* __restrict__ counts,
        int* __restrict__ offsets, int* __restrict__ bsum, int n) {
    __shared__ int sd[1024];
    int tid = threadIdx.x, i = blockIdx.x * 1024 + tid;
    int v = (i < n) ? counts[i] : 0;
    sd[tid] = v; __syncthreads();
    for (int off = 1; off < 1024; off <<= 1) {
        int t = (tid >= off) ? sd[tid - off] : 0; __syncthreads();
        sd[tid] += t; __syncthreads();
    }
    if (i < n) offsets[i] = sd[tid] - v;
    if (tid == 1023) bsum[blockIdx.x] = sd[1023];
}
__global__ void k_scan2(const int* __restrict__ bsum, int* __restrict__ bpref, int nb) {
    if (threadIdx.x == 0) {
        int run = 0;
        for (int i = 0; i < nb; ++i) { bpref[i] = run; run += bsum[i]; }
    }
}
__global__ __launch_bounds__(1024) void k_scan3(int* __restrict__ offsets,
        int* __restrict__ cursor, const int* __restrict__ bpref, int n, int e) {
    int i = blockIdx.x * 1024 + threadIdx.x;
    if (i < n) {
        int v = offsets[i] + bpref[blockIdx.x];
        offsets[i] = v; cursor[i] = v;
    }
    if (i == 0) offsets[n] = e;
}
__global__ void k_permute(const int* __restrict__ src, const int* __restrict__ dst,
                          int* cursor, int* __restrict__ csr, int e) {
    for (int i = blockIdx.x * blockDim.x + threadIdx.x; i < e; i += gridDim.x * blockDim.x) {
        int p = atomicAdd(&cursor[dst[i]], 1);
        csr[p] = src[i];
    }
}

// ---------------- per-dst gather: 16-lane group per dst, 4 dst/wave ----------------
template <bool OUT_F32, bool RELU>
__global__ __launch_bounds__(256) void k_gather3(const __bf16* __restrict__ xw,
        const int* __restrict__ offsets, const int* __restrict__ csr,
        const float* __restrict__ bias, void* __restrict__ outp, int n) {
    const int gg = (blockIdx.x << 4) | (threadIdx.x >> 4);
    const int l = threadIdx.x & 15;
    if (gg >= n) return;
    const int s = offsets[gg], e = offsets[gg + 1];
    const u32x4* __restrict__ xq = (const u32x4*)xw;   // 16 quads per 128-bf16 row
    float a[8] = {0,0,0,0,0,0,0,0};
    int i = s;
    for (; i + 4 <= e; i += 4) {
        u32x4 v0 = xq[(size_t)csr[i]     * 16 + l];
        u32x4 v1 = xq[(size_t)csr[i + 1] * 16 + l];
        u32x4 v2 = xq[(size_t)csr[i + 2] * 16 + l];
        u32x4 v3 = xq[(size_t)csr[i + 3] * 16 + l];
#pragma unroll
        for (int k = 0; k < 4; ++k) {
            a[2 * k]     += (bf_lo(v0[k]) + bf_lo(v1[k])) + (bf_lo(v2[k]) + bf_lo(v3[k]));
            a[2 * k + 1] += (bf_hi(v0[k]) + bf_hi(v1[k])) + (bf_hi(v2[k]) + bf_hi(v3[k]));
        }
    }
    for (; i < e; ++i) {
        u32x4 v = xq[(size_t)csr[i] * 16 + l];
#pragma unroll
        for (int k = 0; k < 4; ++k) { a[2 * k] += bf_lo(v[k]); a[2 * k + 1] += bf_hi(v[k]); }
    }
    const float4 b0 = *(const float4*)(bias + l * 8);
    const float4 b1 = *(const float4*)(bias + l * 8 + 4);
    float r[8] = {a[0] + b0.x, a[1] + b0.y, a[2] + b0.z, a[3] + b0.w,
                  a[4] + b1.x, a[5] + b1.y, a[6] + b1.z, a[7] + b1.w};
    if (RELU) {
#pragma unroll
        for (int k = 0; k < 8; ++k) r[k] = fmaxf(r[k], 0.f);
    }
    if (OUT_F32) {
        float* o = (float*)outp + (size_t)gg * D + l * 8;
        *(float4*)o       = make_float4(r[0], r[1], r[2], r[3]);
        *(float4*)(o + 4) = make_float4(r[4], r[5], r[6], r[7]);
    } else {
        bf16x8 b;
#pragma unroll
        for (int k = 0; k < 8; ++k) b[k] = (__bf16)r[k];
        *(bf16x8*)((__bf16*)outp + (size_t)gg * D + l * 8) = b;
    }
}

extern "C" void kernel_launch(void* const* d_in, const int* in_sizes, int n_in,
                              void* d_out, int out_size, void* d_ws, size_t ws_size,
                              hipStream_t stream) {
    const float* xin = (const float*)d_in[0];
    const int*   edges = (const int*)d_in[1];
    const float* Wih = (const float*)d_in[2];
    const float* Whh = (const float*)d_in[3];
    const float* bih = (const float*)d_in[4];
    const float* bhh = (const float*)d_in[5];
    const float* W1  = (const float*)d_in[6];
    const float* b1  = (const float*)d_in[7];
    const float* W2  = (const float*)d_in[8];
    const float* b2  = (const float*)d_in[9];
    float* outp = (float*)d_out;

    const int E = in_sizes[1] / 2;
    const int n = out_size / D;                 // 50000
    const int tsteps = in_sizes[0] / (n * D);   // 16
    const int* srcE = edges;
    const int* dstE = edges + E;

    char* ws = (char*)d_ws;
    size_t off = 0;
    auto alloc = [&](size_t bytes) { void* p = ws + off; off += (bytes + 511) & ~(size_t)511; return p; };
    __bf16* Wcomb = (__bf16*)alloc((size_t)G4 * KK * 2);
    __bf16* W1t   = (__bf16*)alloc((size_t)D * D * 2);
    __bf16* W2t   = (__bf16*)alloc((size_t)D * D * 2);
    float*  bcomb = (float*)alloc((size_t)G4 * 4);
    int* counts  = (int*)alloc((size_t)(n + 1) * 4);
    int* offsets = (int*)alloc((size_t)(n + 1) * 4);
    int* cursor  = (int*)alloc((size_t)(n + 1) * 4);
    int* bsum    = (int*)alloc(64 * 4);
    int* bpref   = (int*)alloc(64 * 4);
    int* csr     = (int*)alloc((size_t)E * 4);
    __bf16* xw1  = (__bf16*)alloc((size_t)n * D * 2);
    __bf16* out1 = (__bf16*)alloc((size_t)n * D * 2);
    __bf16* xw2  = xw1;   // reuse: xw1 dead after layer-1 gather
    (void)ws_size; (void)n_in;

    {
        int total = G4 * KK + 2 * D * D + G4;
        k_prep<<<(total + 255) / 256, 256, 0, stream>>>(Wih, Whh, bih, bhh, W1, W2,
                                                        Wcomb, W1t, W2t, bcomb);
    }
    hipMemsetAsync(counts, 0, (size_t)n * 4, stream);
    k_hist<<<2048, 256, 0, stream>>>(dstE, counts, E);
    int nb = (n + 1023) / 1024;
    k_scan1<<<nb, 1024, 0, stream>>>(counts, offsets, bsum, n);
    k_scan2<<<1, 64, 0, stream>>>(bsum, bpref, nb);
    k_scan3<<<nb, 1024, 0, stream>>>(offsets, cursor, bpref, n, E);
    k_permute<<<2048, 256, 0, stream>>>(srcE, dstE, cursor, csr, E);

    const int nchunks = n / 16;                       // 3125
    const int npairs = (nchunks + 1) / 2;             // 1563
    k_lstm3<<<256, 512, 0, stream>>>(xin, Wcomb, bcomb, W1t, xw1, n, tsteps, npairs, nchunks);

    k_gather3<false, true><<<(n + 15) / 16, 256, 0, stream>>>(xw1, offsets, csr, b1, out1, n);
    k_gemm2<<<((n / 16) + 3) / 4, 256, 0, stream>>>(out1, W2t, xw2, n);
    k_gather3<true, false><<<(n + 15) / 16, 256, 0, stream>>>(xw2, offsets, csr, b2, outp, n);
}

// Round 5
// 1025.821 us; speedup vs baseline: 4.3928x; 1.0169x over previous
//
#include <hip/hip_runtime.h>
#include <hip/hip_bf16.h>

#define D 128
#define G4 512   // 4*D
#define KK 256   // D + D (x part + h part)
#define LROW 144 // padded LDS row (bf16 elems): 288B -> rows spread across banks

typedef __attribute__((ext_vector_type(4))) float f32x4;
typedef __attribute__((ext_vector_type(8))) __bf16 bf16x8;
typedef __attribute__((ext_vector_type(4))) __bf16 bf16x4;
typedef __attribute__((ext_vector_type(4))) unsigned int u32x4;

// MFMA D[16 dims][16 nodes] += A(W, AGPR) * B(act, VGPR); acc stays in VGPR.
#define MFMA_AV(acc, wf, xf) \
    asm volatile("v_mfma_f32_16x16x32_bf16 %0, %1, %2, %0" : "+v"(acc) : "a"(wf), "v"(xf))
#define MFMA_VV(acc, wf, xf) \
    asm volatile("v_mfma_f32_16x16x32_bf16 %0, %1, %2, %0" : "+v"(acc) : "v"(wf), "v"(xf))

__device__ __forceinline__ float sigm2(float x) {
    return __builtin_amdgcn_rcpf(1.0f + __builtin_amdgcn_exp2f(-1.4426950408889634f * x));
}
__device__ __forceinline__ float tanh2(float x) {
    return 1.0f - 2.0f * __builtin_amdgcn_rcpf(1.0f + __builtin_amdgcn_exp2f(2.8853900817779268f * x));
}
__device__ __forceinline__ float bf_lo(unsigned int u) { return __uint_as_float(u << 16); }
__device__ __forceinline__ float bf_hi(unsigned int u) { return __uint_as_float(u & 0xffff0000u); }

// ---------------- weight packing ----------------
__global__ void k_prep(const float* __restrict__ Wih, const float* __restrict__ Whh,
                       const float* __restrict__ bih, const float* __restrict__ bhh,
                       const float* __restrict__ W1, const float* __restrict__ W2,
                       __bf16* __restrict__ Wcomb, __bf16* __restrict__ W1t,
                       __bf16* __restrict__ W2t, float* __restrict__ bcomb) {
    int t = blockIdx.x * blockDim.x + threadIdx.x;
    if (t < G4 * KK) {
        int row = t / KK, k = t % KK;
        float v = (k < D) ? Wih[row * D + k] : Whh[row * D + (k - D)];
        Wcomb[t] = (__bf16)v;
    } else if (t < G4 * KK + D * D) {
        int u = t - G4 * KK; int o = u / D, k = u % D;
        W1t[u] = (__bf16)W1[k * D + o];
    } else if (t < G4 * KK + 2 * D * D) {
        int u = t - G4 * KK - D * D; int o = u / D, k = u % D;
        W2t[u] = (__bf16)W2[k * D + o];
    } else if (t < G4 * KK + 2 * D * D + G4) {
        int u = t - G4 * KK - 2 * D * D;
        bcomb[u] = bih[u] + bhh[u];
    }
}

// ---------------- persistent LSTM v4: AGPR weights, swapped-operand MFMA ----------------
// Block = 8 waves, 2 node-chunks interleaved. Wave w holds (as MFMA A-operand, in
// 128 AGPRs) Wcomb rows {g*128 + w*16 + c16} over K=256. D = W * [x;h]^T gives
// lane (q,c16): dims w*16+q*4+j (j=0..3), node c16 -> h-write is one b64; biases
// pre-loaded into acc via broadcast LDS reads. x/h in 288B-padded LDS rows.
__global__ __launch_bounds__(512, 2) void k_lstm4(
        const float* __restrict__ xin, const __bf16* __restrict__ Wcomb,
        const float* __restrict__ bcomb, const __bf16* __restrict__ W1t,
        __bf16* __restrict__ xw1, int n, int tsteps, int npairs, int nchunks) {
    __shared__ __align__(16) float  sbias[G4];
    __shared__ __align__(16) __bf16 xb[2][2][16][LROW];   // [chunk][dbuf][node][elem]
    __shared__ __align__(16) __bf16 hb[2][2][16][LROW];

    const int tid = threadIdx.x;
    const int wid = tid >> 6, l = tid & 63, q = l >> 4, c16 = l & 15;
    const int q8 = q * 8;
    const int wrow = wid * 16 + c16;        // weight row within each gate tile
    const int w16q4 = wid * 16 + q * 4;     // dim base this lane produces

    // resident weights (AGPR via "a" uses): Wf[g][kb] = A-frag rows g*128+wrow, K-slice kb
    bf16x8 Wf[4][8];
#pragma unroll
    for (int g = 0; g < 4; ++g)
#pragma unroll
        for (int kb = 0; kb < 8; ++kb)
            Wf[g][kb] = *(const bf16x8*)(Wcomb + (size_t)(g * D + wrow) * KK + kb * 32 + q8);

    if (tid < G4) sbias[tid] = bcomb[tid];

    const int sid = tid >> 8;               // which chunk this thread stages
    const int su = tid & 255;
    const int srow = su >> 4, sc8 = (su & 15) * 8;

    for (int p = blockIdx.x; p < npairs; p += gridDim.x) {
        const int cA = 2 * p, cB = 2 * p + 1;
        const bool hasB = (cB < nchunks);
        const int myc = sid ? (hasB ? cB : cA) : cA;

        // h0 = 0; stage x(0)
        {
            bf16x8 z = {};
            *(bf16x8*)&hb[sid][0][srow][sc8] = z;
            const float* xp = xin + ((size_t)(myc * 16 + srow)) * D + sc8;
            float4 v0 = *(const float4*)xp, v1 = *(const float4*)(xp + 4);
            bf16x8 b;
            b[0] = (__bf16)v0.x; b[1] = (__bf16)v0.y; b[2] = (__bf16)v0.z; b[3] = (__bf16)v0.w;
            b[4] = (__bf16)v1.x; b[5] = (__bf16)v1.y; b[6] = (__bf16)v1.z; b[7] = (__bf16)v1.w;
            *(bf16x8*)&xb[sid][0][srow][sc8] = b;
        }
        __syncthreads();

        float csA[4] = {0.f, 0.f, 0.f, 0.f}, csB[4] = {0.f, 0.f, 0.f, 0.f};

        for (int t0 = 0; t0 < tsteps; t0 += 2) {
#pragma unroll
            for (int tt = 0; tt < 2; ++tt) {
                const int t = t0 + tt, cur = tt, nxt = tt ^ 1;

                // acc init = bias (broadcast LDS read; D-layout row = dim w16q4+j)
                f32x4 accA[4], accB[4];
#pragma unroll
                for (int g = 0; g < 4; ++g) {
                    accA[g] = *(const f32x4*)&sbias[g * D + w16q4];
                    accB[g] = accA[g];
                }

                // prefetch x(t+1) (latency hidden under MFMA block)
                float4 px0, px1;
                const bool pf = (t + 1 < tsteps);
                if (pf) {
                    const float* xp = xin + ((size_t)(t + 1) * n + myc * 16 + srow) * D + sc8;
                    px0 = *(const float4*)xp; px1 = *(const float4*)(xp + 4);
                }

#pragma unroll
                for (int kb = 0; kb < 8; ++kb) {
                    const int e = (kb & 3) * 32 + q8;
                    bf16x8 fA, fB;
                    if (kb < 4) {
                        fA = *(const bf16x8*)&xb[0][cur][c16][e];
                        fB = *(const bf16x8*)&xb[1][cur][c16][e];
                    } else {
                        fA = *(const bf16x8*)&hb[0][cur][c16][e];
                        fB = *(const bf16x8*)&hb[1][cur][c16][e];
                    }
                    MFMA_AV(accA[0], Wf[0][kb], fA); MFMA_AV(accB[0], Wf[0][kb], fB);
                    MFMA_AV(accA[1], Wf[1][kb], fA); MFMA_AV(accB[1], Wf[1][kb], fB);
                    MFMA_AV(accA[2], Wf[2][kb], fA); MFMA_AV(accB[2], Wf[2][kb], fB);
                    MFMA_AV(accA[3], Wf[3][kb], fA); MFMA_AV(accB[3], Wf[3][kb], fB);
                }
                asm volatile("s_nop 7\n\ts_nop 7");   // MFMA -> VALU read hazard guard

                // store prefetched x
                if (pf) {
                    bf16x8 b;
                    b[0] = (__bf16)px0.x; b[1] = (__bf16)px0.y; b[2] = (__bf16)px0.z; b[3] = (__bf16)px0.w;
                    b[4] = (__bf16)px1.x; b[5] = (__bf16)px1.y; b[6] = (__bf16)px1.z; b[7] = (__bf16)px1.w;
                    *(bf16x8*)&xb[sid][nxt][srow][sc8] = b;
                }

                // cell update chunk A (lane: node c16, dims w16q4+j)
                {
                    bf16x4 hv;
#pragma unroll
                    for (int j = 0; j < 4; ++j) {
                        float iv = sigm2(accA[0][j]);
                        float fv = sigm2(accA[1][j]);
                        float gv = tanh2(accA[2][j]);
                        float ov = sigm2(accA[3][j]);
                        float c = fv * csA[j] + iv * gv;
                        csA[j] = c;
                        hv[j] = (__bf16)(ov * tanh2(c));
                    }
                    *(bf16x4*)&hb[0][nxt][c16][w16q4] = hv;
                }
                // cell update chunk B
                {
                    bf16x4 hv;
#pragma unroll
                    for (int j = 0; j < 4; ++j) {
                        float iv = sigm2(accB[0][j]);
                        float fv = sigm2(accB[1][j]);
                        float gv = tanh2(accB[2][j]);
                        float ov = sigm2(accB[3][j]);
                        float c = fv * csB[j] + iv * gv;
                        csB[j] = c;
                        hv[j] = (__bf16)(ov * tanh2(c));
                    }
                    *(bf16x4*)&hb[1][nxt][c16][w16q4] = hv;
                }
                __syncthreads();
            }
        }

        // epilogue: xw1 = h_final @ W1 (h_final in dbuf 0 for even tsteps)
        f32x4 eA = {0, 0, 0, 0}, eB = {0, 0, 0, 0};
#pragma unroll
        for (int kb = 0; kb < 4; ++kb) {
            bf16x8 w1f = *(const bf16x8*)(W1t + (size_t)wrow * D + kb * 32 + q8);
            bf16x8 hA = *(const bf16x8*)&hb[0][0][c16][kb * 32 + q8];
            bf16x8 hB = *(const bf16x8*)&hb[1][0][c16][kb * 32 + q8];
            MFMA_VV(eA, w1f, hA);
            MFMA_VV(eB, w1f, hB);
        }
        asm volatile("s_nop 7\n\ts_nop 7");
        bf16x4 oA, oB;
#pragma unroll
        for (int j = 0; j < 4; ++j) { oA[j] = (__bf16)eA[j]; oB[j] = (__bf16)eB[j]; }
        *(bf16x4*)(xw1 + (size_t)(cA * 16 + c16) * D + w16q4) = oA;
        if (hasB)
            *(bf16x4*)(xw1 + (size_t)(cB * 16 + c16) * D + w16q4) = oB;
        __syncthreads();   // protect hb/xb before next pair's restage
    }
}

// ---------------- xw2 = out1 @ W2  (out1 already relu'd bf16) ----------------
__global__ __launch_bounds__(256) void k_gemm2(
        const __bf16* __restrict__ in, const __bf16* __restrict__ Wt,
        __bf16* __restrict__ outm, int n) {
    const int tid = threadIdx.x, wid = tid >> 6, l = tid & 63, q = l >> 4, c16 = l & 15;
    const int R = (blockIdx.x * 4 + wid) * 16;
    if (R + 16 > n) return;
    bf16x8 af[4];
#pragma unroll
    for (int kb = 0; kb < 4; ++kb)
        af[kb] = *(const bf16x8*)(in + (size_t)(R + c16) * D + kb * 32 + q * 8);
#pragma unroll
    for (int nt = 0; nt < 8; ++nt) {
        f32x4 acc = {0, 0, 0, 0};
#pragma unroll
        for (int kb = 0; kb < 4; ++kb) {
            const __bf16* wb = Wt + (size_t)(nt * 16 + c16) * D + (kb * 32 + q * 8);
            acc = __builtin_amdgcn_mfma_f32_16x16x32_bf16(af[kb], *(const bf16x8*)wb, acc, 0, 0, 0);
        }
#pragma unroll
        for (int j = 0; j < 4; ++j)
            outm[(size_t)(R + q * 4 + j) * D + nt * 16 + c16] = (__bf16)acc[j];
    }
}

// ---------------- CSR build ----------------
__global__ void k_hist(const int* __restrict__ dst, int* __restrict__ counts, int e) {
    for (int i = blockIdx.x * blockDim.x + threadIdx.x; i < e; i += gridDim.x * blockDim.x)
        atomicAdd(&counts[dst[i]], 1);
}
__global__ __launch_bounds__(1024) void k_scan1(const int* __restrict__ counts,
        int* __restrict__ offsets, int* __restrict__ bsum, int n) {
    __shared__ int sd[1024];
    int tid = threadIdx.x, i = blockIdx.x * 1024 + tid;
    int v = (i < n) ? counts[i] : 0;
    sd[tid] = v; __syncthreads();
    for (int off = 1; off < 1024; off <<= 1) {
        int t = (tid >= off) ? sd[tid - off] : 0; __syncthreads();
        sd[tid] += t; __syncthreads();
    }
    if (i < n) offsets[i] = sd[tid] - v;
    if (tid == 1023) bsum[blockIdx.x] = sd[1023];
}
__global__ void k_scan2(const int* __restrict__ bsum, int* __restrict__ bpref, int nb) {
    if (threadIdx.x == 0) {
        int run = 0;
        for (int i = 0; i < nb; ++i) { bpref[i] = run; run += bsum[i]; }
    }
}
__global__ __launch_bounds__(1024) void k_scan3(int* __restrict__ offsets,
        int* __restrict__ cursor, const int* __restrict__ bpref, int n, int e) {
    int i = blockIdx.x * 1024 + threadIdx.x;
    if (i < n) {
        int v = offsets[i] + bpref[blockIdx.x];
        offsets[i] = v; cursor[i] = v;
    }
    if (i == 0) offsets[n] = e;
}
__global__ void k_permute(const int* __restrict__ src, const int* __restrict__ dst,
                          int* cursor, int* __restrict__ csr, int e) {
    for (int i = blockIdx.x * blockDim.x + threadIdx.x; i < e; i += gridDim.x * blockDim.x) {
        int p = atomicAdd(&cursor[dst[i]], 1);
        csr[p] = src[i];
    }
}

// ---------------- per-dst gather: 16-lane group per dst, unroll 8 ----------------
template <bool OUT_F32, bool RELU>
__global__ __launch_bounds__(256) void k_gather3(const __bf16* __restrict__ xw,
        const int* __restrict__ offsets, const int* __restrict__ csr,
        const float* __restrict__ bias, void* __restrict__ outp, int n) {
    const int gg = (blockIdx.x << 4) | (threadIdx.x >> 4);
    const int l = threadIdx.x & 15;
    if (gg >= n) return;
    const int s = offsets[gg], e = offsets[gg + 1];
    const u32x4* __restrict__ xq = (const u32x4*)xw;   // 16 quads per 128-bf16 row
    float a[8] = {0,0,0,0,0,0,0,0};
    int i = s;
    for (; i + 8 <= e; i += 8) {
        u32x4 v[8];
#pragma unroll
        for (int r = 0; r < 8; ++r) v[r] = xq[(size_t)csr[i + r] * 16 + l];
#pragma unroll
        for (int r = 0; r < 8; ++r)
#pragma unroll
            for (int k = 0; k < 4; ++k) {
                a[2 * k]     += bf_lo(v[r][k]);
                a[2 * k + 1] += bf_hi(v[r][k]);
            }
    }
    for (; i + 2 <= e; i += 2) {
        u32x4 v0 = xq[(size_t)csr[i] * 16 + l];
        u32x4 v1 = xq[(size_t)csr[i + 1] * 16 + l];
#pragma unroll
        for (int k = 0; k < 4; ++k) {
            a[2 * k]     += bf_lo(v0[k]) + bf_lo(v1[k]);
            a[2 * k + 1] += bf_hi(v0[k]) + bf_hi(v1[k]);
        }
    }
    if (i < e) {
        u32x4 v = xq[(size_t)csr[i] * 16 + l];
#pragma unroll
        for (int k = 0; k < 4; ++k) { a[2 * k] += bf_lo(v[k]); a[2 * k + 1] += bf_hi(v[k]); }
    }
    const float4 b0 = *(const float4*)(bias + l * 8);
    const float4 b1 = *(const float4*)(bias + l * 8 + 4);
    float r[8] = {a[0] + b0.x, a[1] + b0.y, a[2] + b0.z, a[3] + b0.w,
                  a[4] + b1.x, a[5] + b1.y, a[6] + b1.z, a[7] + b1.w};
    if (RELU) {
#pragma unroll
        for (int k = 0; k < 8; ++k) r[k] = fmaxf(r[k], 0.f);
    }
    if (OUT_F32) {
        float* o = (float*)outp + (size_t)gg * D + l * 8;
        *(float4*)o       = make_float4(r[0], r[1], r[2], r[3]);
        *(float4*)(o + 4) = make_float4(r[4], r[5], r[6], r[7]);
    } else {
        bf16x8 b;
#pragma unroll
        for (int k = 0; k < 8; ++k) b[k] = (__bf16)r[k];
        *(bf16x8*)((__bf16*)outp + (size_t)gg * D + l * 8) = b;
    }
}

extern "C" void kernel_launch(void* const* d_in, const int* in_sizes, int n_in,
                              void* d_out, int out_size, void* d_ws, size_t ws_size,
                              hipStream_t stream) {
    const float* xin = (const float*)d_in[0];
    const int*   edges = (const int*)d_in[1];
    const float* Wih = (const float*)d_in[2];
    const float* Whh = (const float*)d_in[3];
    const float* bih = (const float*)d_in[4];
    const float* bhh = (const float*)d_in[5];
    const float* W1  = (const float*)d_in[6];
    const float* b1  = (const float*)d_in[7];
    const float* W2  = (const float*)d_in[8];
    const float* b2  = (const float*)d_in[9];
    float* outp = (float*)d_out;

    const int E = in_sizes[1] / 2;
    const int n = out_size / D;                 // 50000
    const int tsteps = in_sizes[0] / (n * D);   // 16
    const int* srcE = edges;
    const int* dstE = edges + E;

    char* ws = (char*)d_ws;
    size_t off = 0;
    auto alloc = [&](size_t bytes) { void* p = ws + off; off += (bytes + 511) & ~(size_t)511; return p; };
    __bf16* Wcomb = (__bf16*)alloc((size_t)G4 * KK * 2);
    __bf16* W1t   = (__bf16*)alloc((size_t)D * D * 2);
    __bf16* W2t   = (__bf16*)alloc((size_t)D * D * 2);
    float*  bcomb = (float*)alloc((size_t)G4 * 4);
    int* counts  = (int*)alloc((size_t)(n + 1) * 4);
    int* offsets = (int*)alloc((size_t)(n + 1) * 4);
    int* cursor  = (int*)alloc((size_t)(n + 1) * 4);
    int* bsum    = (int*)alloc(64 * 4);
    int* bpref   = (int*)alloc(64 * 4);
    int* csr     = (int*)alloc((size_t)E * 4);
    __bf16* xw1  = (__bf16*)alloc((size_t)n * D * 2);
    __bf16* out1 = (__bf16*)alloc((size_t)n * D * 2);
    __bf16* xw2  = xw1;   // reuse: xw1 dead after layer-1 gather
    (void)ws_size; (void)n_in;

    {
        int total = G4 * KK + 2 * D * D + G4;
        k_prep<<<(total + 255) / 256, 256, 0, stream>>>(Wih, Whh, bih, bhh, W1, W2,
                                                        Wcomb, W1t, W2t, bcomb);
    }
    hipMemsetAsync(counts, 0, (size_t)n * 4, stream);
    k_hist<<<2048, 256, 0, stream>>>(dstE, counts, E);
    int nb = (n + 1023) / 1024;
    k_scan1<<<nb, 1024, 0, stream>>>(counts, offsets, bsum, n);
    k_scan2<<<1, 64, 0, stream>>>(bsum, bpref, nb);
    k_scan3<<<nb, 1024, 0, stream>>>(offsets, cursor, bpref, n, E);
    k_permute<<<2048, 256, 0, stream>>>(srcE, dstE, cursor, csr, E);

    const int nchunks = n / 16;                       // 3125
    const int npairs = (nchunks + 1) / 2;             // 1563
    k_lstm4<<<256, 512, 0, stream>>>(xin, Wcomb, bcomb, W1t, xw1, n, tsteps, npairs, nchunks);

    k_gather3<false, true><<<(n + 15) / 16, 256, 0, stream>>>(xw1, offsets, csr, b1, out1, n);
    k_gemm2<<<((n / 16) + 3) / 4, 256, 0, stream>>>(out1, W2t, xw2, n);
    k_gather3<true, false><<<(n + 15) / 16, 256, 0, stream>>>(xw2, offsets, csr, b2, outp, n);
}